// Round 2
// baseline (1768.985 us; speedup 1.0000x reference)
//
#include <hip/hip_runtime.h>

// GPT2 decode block, fp32 in/out (matching reference dtypes exactly).
// B=32, H=2048, NH=16, HD=128, DFF=8192, paged KV: 1024 blocks x 64 tok.

#define BB     32
#define HDIM   2048
#define NH     16
#define HD     128
#define DFF    8192
#define NBLK   1024
#define BLKSZ  64
#define MAXB   32
#define MAXS   2048

__device__ __forceinline__ float wave_sum(float v) {
    for (int s = 1; s < 64; s <<= 1) v += __shfl_xor(v, s, 64);
    return v;
}
__device__ __forceinline__ float wave_max(float v) {
    for (int s = 1; s < 64; s <<= 1) v = fmaxf(v, __shfl_xor(v, s, 64));
    return v;
}

// ---------------- LayerNorm 1: x1 = LN(hidden)*g + b ------------------------
__global__ __launch_bounds__(256) void ln1_kernel(
    const float* __restrict__ xin, const float* __restrict__ g,
    const float* __restrict__ bb, float* __restrict__ out) {
    int row = blockIdx.x, tid = threadIdx.x, wave = tid >> 6, lane = tid & 63;
    __shared__ float red[4], red2[4];
    int base = row * HDIM + tid * 8;
    const float4* x4 = (const float4*)(xin + base);
    float4 a = x4[0], c = x4[1];
    float v[8] = {a.x, a.y, a.z, a.w, c.x, c.y, c.z, c.w};
    float s = 0;
#pragma unroll
    for (int i = 0; i < 8; ++i) s += v[i];
    s = wave_sum(s);
    if (lane == 0) red[wave] = s;
    __syncthreads();
    float mu = (red[0] + red[1] + red[2] + red[3]) * (1.0f / HDIM);
    float s2 = 0;
#pragma unroll
    for (int i = 0; i < 8; ++i) { float d = v[i] - mu; s2 += d * d; }
    s2 = wave_sum(s2);
    if (lane == 0) red2[wave] = s2;
    __syncthreads();
    float rs = rsqrtf((red2[0] + red2[1] + red2[2] + red2[3]) * (1.0f / HDIM) + 1e-5f);
    const float4* g4 = (const float4*)(g + tid * 8);
    const float4* b4 = (const float4*)(bb + tid * 8);
    float4 ga = g4[0], gc = g4[1], ba = b4[0], bc = b4[1];
    float gv[8] = {ga.x, ga.y, ga.z, ga.w, gc.x, gc.y, gc.z, gc.w};
    float bv[8] = {ba.x, ba.y, ba.z, ba.w, bc.x, bc.y, bc.z, bc.w};
    float o[8];
#pragma unroll
    for (int i = 0; i < 8; ++i) o[i] = (v[i] - mu) * rs * gv[i] + bv[i];
    float4* o4 = (float4*)(out + base);
    o4[0] = make_float4(o[0], o[1], o[2], o[3]);
    o4[1] = make_float4(o[4], o[5], o[6], o[7]);
}

// ---------------- Skinny GEMM with K-split + atomic accumulate ----------------
// X fp32 [32,K], W fp32 [K x N] row-major stride ldw, out fp32 [32,N] (+=).
// Wave handles 8 rows of X; lane handles 4 consecutive cols (float4).
// Block tile: 256 cols. grid.x = N/256, grid.y = K/kslice.
__global__ __launch_bounds__(256) void gemm_atomic(
    const float* __restrict__ X, const float* __restrict__ W,
    float* __restrict__ out, int K, int N, int ldw, int kslice) {
    int lane = threadIdx.x & 63;
    int mg = __builtin_amdgcn_readfirstlane(threadIdx.x >> 6);
    int nbase = blockIdx.x * 256 + lane * 4;
    int k0 = blockIdx.y * kslice, k1 = k0 + kslice;
    const float* Xr = X + mg * 8 * K;
    float acc[8][4];
#pragma unroll
    for (int r = 0; r < 8; ++r)
#pragma unroll
        for (int c = 0; c < 4; ++c) acc[r][c] = 0.f;
    const float* Wp = W + (size_t)k0 * ldw + nbase;
#pragma unroll 4
    for (int k = k0; k < k1; ++k) {
        float4 wv = *(const float4*)Wp;
        Wp += ldw;
#pragma unroll
        for (int r = 0; r < 8; ++r) {
            float xv = Xr[r * K + k];
            acc[r][0] += xv * wv.x;
            acc[r][1] += xv * wv.y;
            acc[r][2] += xv * wv.z;
            acc[r][3] += xv * wv.w;
        }
    }
#pragma unroll
    for (int r = 0; r < 8; ++r) {
        float* op = out + (size_t)(mg * 8 + r) * N + nbase;
#pragma unroll
        for (int c = 0; c < 4; ++c) unsafeAtomicAdd(op + c, acc[r][c]);
    }
}

// ---------------- Decode attention, one block per (head, batch) --------------
__global__ __launch_bounds__(512) void attn_kernel(
    const float* __restrict__ qp, const float* __restrict__ b_attn,
    const float* __restrict__ kv, const int* __restrict__ bt,
    const int* __restrict__ sl, float* __restrict__ out) {
    int h = blockIdx.x, b = blockIdx.y;
    int tid = threadIdx.x, wave = tid >> 6, lane = tid & 63;
    __shared__ float s_sc[MAXS];
    __shared__ int s_bt[MAXB];
    __shared__ float s_red[8];
    __shared__ float s_pv[8][HD];
    int L = sl[b];
    if (tid < MAXB) s_bt[tid] = bt[b * MAXB + tid];
    int d0 = lane * 2;
    float2 qv = *(const float2*)(qp + b * HDIM + h * HD + d0);
    float2 qb = *(const float2*)(b_attn + h * HD + d0);
    float q0 = qv.x + qb.x, q1 = qv.y + qb.y;
    __syncthreads();
    const float* Kc = kv;
    const float* Vc = kv + (size_t)NBLK * BLKSZ * NH * HD;
    const float scale = 0.088388347648318447f;  // 1/sqrt(128)
    for (int t = wave; t < L; t += 8) {
        int blk = s_bt[t >> 6];
        size_t base = ((size_t)(blk * BLKSZ + (t & 63)) * NH + h) * HD + d0;
        float2 kvv = *(const float2*)(Kc + base);
        float dot = q0 * kvv.x + q1 * kvv.y;
        dot = wave_sum(dot);
        if (lane == 0) s_sc[t] = dot * scale;
    }
    __syncthreads();
    // softmax over s_sc[0..L)
    float m = -1e30f;
    for (int i = tid; i < L; i += 512) m = fmaxf(m, s_sc[i]);
    m = wave_max(m);
    if (lane == 0) s_red[wave] = m;
    __syncthreads();
    m = s_red[0];
#pragma unroll
    for (int w = 1; w < 8; ++w) m = fmaxf(m, s_red[w]);
    float ssum = 0;
    for (int i = tid; i < L; i += 512) {
        float e = __expf(s_sc[i] - m);
        s_sc[i] = e;
        ssum += e;
    }
    ssum = wave_sum(ssum);
    __syncthreads();
    if (lane == 0) s_red[wave] = ssum;
    __syncthreads();
    float tot = 0;
#pragma unroll
    for (int w = 0; w < 8; ++w) tot += s_red[w];
    float inv = 1.0f / tot;
    float a0 = 0, a1 = 0;
    for (int t = wave; t < L; t += 8) {
        int blk = s_bt[t >> 6];
        size_t base = ((size_t)(blk * BLKSZ + (t & 63)) * NH + h) * HD + d0;
        float2 vvv = *(const float2*)(Vc + base);
        float p = s_sc[t];
        a0 += p * vvv.x;
        a1 += p * vvv.y;
    }
    s_pv[wave][d0] = a0;
    s_pv[wave][d0 + 1] = a1;
    __syncthreads();
    if (wave == 0) {
        float r0 = 0, r1 = 0;
#pragma unroll
        for (int w = 0; w < 8; ++w) { r0 += s_pv[w][d0]; r1 += s_pv[w][d0 + 1]; }
        out[b * HDIM + h * HD + d0] = r0 * inv;
        out[b * HDIM + h * HD + d0 + 1] = r1 * inv;
    }
}

// ------------- h = proj_part + b_proj + hidden;  x2 = LN(h)*g + b ------------
__global__ __launch_bounds__(256) void ep_h_ln2(
    const float* __restrict__ pp, const float* __restrict__ bproj,
    const float* __restrict__ hid, const float* __restrict__ g,
    const float* __restrict__ bb, float* __restrict__ hout,
    float* __restrict__ x2) {
    int row = blockIdx.x, tid = threadIdx.x, wave = tid >> 6, lane = tid & 63;
    __shared__ float red[4], red2[4];
    int base = row * HDIM + tid * 8;
    const float4* p4 = (const float4*)(pp + base);
    float4 pa = p4[0], pb = p4[1];
    const float4* h4i = (const float4*)(hid + base);
    float4 ha = h4i[0], hb = h4i[1];
    const float4* bp4 = (const float4*)(bproj + tid * 8);
    float4 bpa = bp4[0], bpb = bp4[1];
    float v[8];
    v[0] = pa.x + bpa.x + ha.x;
    v[1] = pa.y + bpa.y + ha.y;
    v[2] = pa.z + bpa.z + ha.z;
    v[3] = pa.w + bpa.w + ha.w;
    v[4] = pb.x + bpb.x + hb.x;
    v[5] = pb.y + bpb.y + hb.y;
    v[6] = pb.z + bpb.z + hb.z;
    v[7] = pb.w + bpb.w + hb.w;
    float4* h4 = (float4*)(hout + base);
    h4[0] = make_float4(v[0], v[1], v[2], v[3]);
    h4[1] = make_float4(v[4], v[5], v[6], v[7]);
    float s = 0;
#pragma unroll
    for (int i = 0; i < 8; ++i) s += v[i];
    s = wave_sum(s);
    if (lane == 0) red[wave] = s;
    __syncthreads();
    float mu = (red[0] + red[1] + red[2] + red[3]) * (1.0f / HDIM);
    float s2 = 0;
#pragma unroll
    for (int i = 0; i < 8; ++i) { float d = v[i] - mu; s2 += d * d; }
    s2 = wave_sum(s2);
    if (lane == 0) red2[wave] = s2;
    __syncthreads();
    float rs = rsqrtf((red2[0] + red2[1] + red2[2] + red2[3]) * (1.0f / HDIM) + 1e-5f);
    const float4* g4 = (const float4*)(g + tid * 8);
    const float4* b4 = (const float4*)(bb + tid * 8);
    float4 ga = g4[0], gc = g4[1], ba = b4[0], bc = b4[1];
    float gv[8] = {ga.x, ga.y, ga.z, ga.w, gc.x, gc.y, gc.z, gc.w};
    float bv[8] = {ba.x, ba.y, ba.z, ba.w, bc.x, bc.y, bc.z, bc.w};
    float o[8];
#pragma unroll
    for (int i = 0; i < 8; ++i) o[i] = (v[i] - mu) * rs * gv[i] + bv[i];
    float4* o4 = (float4*)(x2 + base);
    o4[0] = make_float4(o[0], o[1], o[2], o[3]);
    o4[1] = make_float4(o[4], o[5], o[6], o[7]);
}

// ---------------- y = gelu_exact(fc1_part + b_fc) ----------------------------
__global__ __launch_bounds__(256) void ep_gelu(
    const float* __restrict__ part, const float* __restrict__ bfc,
    float* __restrict__ y) {
    int idx = (blockIdx.x * 256 + threadIdx.x) * 8;
    const float4* p4 = (const float4*)(part + idx);
    float4 a = p4[0], c = p4[1];
    int col = idx & (DFF - 1);
    const float4* b4 = (const float4*)(bfc + col);
    float4 ba = b4[0], bc = b4[1];
    float t[8] = {a.x + ba.x, a.y + ba.y, a.z + ba.z, a.w + ba.w,
                  c.x + bc.x, c.y + bc.y, c.z + bc.z, c.w + bc.w};
#pragma unroll
    for (int i = 0; i < 8; ++i) {
        float u = t[i];
        t[i] = 0.5f * u * (1.0f + erff(u * 0.70710678118654752f));
    }
    float4* o4 = (float4*)(y + idx);
    o4[0] = make_float4(t[0], t[1], t[2], t[3]);
    o4[1] = make_float4(t[4], t[5], t[6], t[7]);
}

// ---------------- out = fc2_part + b_fc2 + h ---------------------------------
__global__ __launch_bounds__(256) void ep_out(
    const float* __restrict__ part, const float* __restrict__ b2,
    const float* __restrict__ h, float* __restrict__ out) {
    int idx = (blockIdx.x * 256 + threadIdx.x) * 8;
    const float4* p4 = (const float4*)(part + idx);
    float4 a = p4[0], c = p4[1];
    const float4* h4 = (const float4*)(h + idx);
    float4 ha = h4[0], hb = h4[1];
    int col = idx & (HDIM - 1);
    const float4* b4 = (const float4*)(b2 + col);
    float4 ba = b4[0], bc = b4[1];
    float4* o4 = (float4*)(out + idx);
    o4[0] = make_float4(a.x + ba.x + ha.x, a.y + ba.y + ha.y,
                        a.z + ba.z + ha.z, a.w + ba.w + ha.w);
    o4[1] = make_float4(c.x + bc.x + hb.x, c.y + bc.y + hb.y,
                        c.z + bc.z + hb.z, c.w + bc.w + hb.w);
}

extern "C" void kernel_launch(void* const* d_in, const int* in_sizes, int n_in,
                              void* d_out, int out_size, void* d_ws, size_t ws_size,
                              hipStream_t stream) {
    (void)in_sizes; (void)n_in; (void)out_size; (void)ws_size;
    const float* hidden = (const float*)d_in[0];
    const float* kv     = (const float*)d_in[1];
    const int* bt = (const int*)d_in[2];
    const int* sl = (const int*)d_in[3];
    const float* ln1g = (const float*)d_in[5];
    const float* ln1b = (const float*)d_in[6];
    const float* ln2g = (const float*)d_in[7];
    const float* ln2b = (const float*)d_in[8];
    const float* w_attn = (const float*)d_in[9];
    const float* b_attn = (const float*)d_in[10];
    const float* w_proj = (const float*)d_in[11];
    const float* b_proj = (const float*)d_in[12];
    const float* w_fc   = (const float*)d_in[13];
    const float* b_fc   = (const float*)d_in[14];
    const float* w_fc2  = (const float*)d_in[15];
    const float* b_fc2  = (const float*)d_in[16];

    float* ws = (float*)d_ws;
    // atomic-accumulated partials (must be zeroed): contiguous region first.
    float* q_part    = ws;                 // 32*2048
    float* proj_part = ws + 65536;         // 32*2048
    float* fc1_part  = ws + 131072;        // 32*8192
    float* fc2_part  = ws + 393216;        // 32*2048
    // plain intermediates:
    float* x1       = ws + 458752;         // 32*2048
    float* attn_out = ws + 524288;         // 32*2048
    float* hbuf     = ws + 589824;         // 32*2048
    float* x2       = ws + 655360;         // 32*2048
    float* y        = ws + 720896;         // 32*8192

    hipMemsetAsync(d_ws, 0, 458752 * sizeof(float), stream);

    ln1_kernel<<<BB, 256, 0, stream>>>(hidden, ln1g, ln1b, x1);
    // q = x1 @ w_attn[:, :2048]   (only the Q slice is ever used)
    gemm_atomic<<<dim3(8, 32), 256, 0, stream>>>(x1, w_attn, q_part, 2048, 2048, 6144, 64);
    attn_kernel<<<dim3(NH, BB), 512, 0, stream>>>(q_part, b_attn, kv, bt, sl, attn_out);
    gemm_atomic<<<dim3(8, 32), 256, 0, stream>>>(attn_out, w_proj, proj_part, 2048, 2048, 2048, 64);
    ep_h_ln2<<<BB, 256, 0, stream>>>(proj_part, b_proj, hidden, ln2g, ln2b, hbuf, x2);
    gemm_atomic<<<dim3(32, 8), 256, 0, stream>>>(x2, w_fc, fc1_part, 2048, 8192, 8192, 256);
    ep_gelu<<<128, 256, 0, stream>>>(fc1_part, b_fc, y);
    gemm_atomic<<<dim3(8, 32), 256, 0, stream>>>(y, w_fc2, fc2_part, 8192, 2048, 2048, 256);
    ep_out<<<BB, 256, 0, stream>>>(fc2_part, b_fc2, hbuf, (float*)d_out);
}